// Round 10
// baseline (442.689 us; speedup 1.0000x reference)
//
#include <hip/hip_runtime.h>
#include <math.h>

// Problem geometry (fixed by the reference)
#define NB 2
#define NVOICE 8
#define NN (NB * NVOICE)   // 16 series
#define NH 64              // harmonics
#define NF 500             // frames
#define NT 32000           // samples
#define NCHUNK 32          // angular_cumsum chunks of 1000
#define CHUNK 1000
#define NWIN 500           // one 64-sample window per synthesis block
#define WIN 64
#define K2BLOCKS (NN * NCHUNK)   // 512 chunk-scan blocks
#define K1BLOCKS (NN * 8)        // 128 normalization blocks
#define REP 16                   // DIAGNOSTIC: x16 internal repeat to surface dispatches in rocprof

static __device__ __forceinline__ float tpi_f()    { return (float)(6.283185307179586); }
static __device__ __forceinline__ float omc_f()    { return (float)(6.283185307179586 / 16000.0); }
static __device__ __forceinline__ float inv2pi_f() { return (float)(1.0 / 6.283185307179586); }

// ---- compile-time Hann window table (f64 Taylor cos, rounded to f32) ----
constexpr double kPIO2 = 1.5707963267948966;
constexpr double d_cos_red(double r) {
    double r2 = r * r, term = 1.0, sum = 1.0;
    for (int k = 1; k <= 12; ++k) { term *= -r2 / (double)((2 * k - 1) * (2 * k)); sum += term; }
    return sum;
}
constexpr double d_sin_red(double r) {
    double r2 = r * r, term = r, sum = r;
    for (int k = 1; k <= 12; ++k) { term *= -r2 / (double)((2 * k) * (2 * k + 1)); sum += term; }
    return sum;
}
constexpr double d_cos(double x) {
    int k = 0; double r = x;
    while (r > kPIO2 * 0.5) { r -= kPIO2; ++k; }
    switch (k & 3) {
        case 0: return d_cos_red(r);
        case 1: return -d_sin_red(r);
        case 2: return -d_cos_red(r);
        default: return d_sin_red(r);
    }
}
struct WinT { float wA[64]; float wB[64]; };
constexpr WinT make_win() {
    WinT w{};
    for (int j = 0; j < 64; ++j) {
        float aA = (float)6.283185307179586 * (float)j * 0.0078125f;
        float aB = (float)6.283185307179586 * (float)(j + 64) * 0.0078125f;
        w.wA[j] = 0.5f - 0.5f * (float)d_cos((double)aA);   // win[r]    -> weights frame q+1
        w.wB[j] = 0.5f - 0.5f * (float)d_cos((double)aB);   // win[64+r] -> weights frame q
    }
    return w;
}
constexpr WinT WT = make_win();

// DPP helpers
template<int CTRL, int RMASK>
static __device__ __forceinline__ float dpp0_add(float x) {
    int y = __builtin_amdgcn_update_dpp(0, __float_as_int(x), CTRL, RMASK, 0xF, true);
    return x + __int_as_float(y);
}
// Inclusive 64-lane prefix sum (Hillis-Steele via DPP)
static __device__ __forceinline__ float wave_incl_scan(float x) {
    x = dpp0_add<0x111, 0xF>(x);   // row_shr:1
    x = dpp0_add<0x112, 0xF>(x);   // row_shr:2
    x = dpp0_add<0x114, 0xF>(x);   // row_shr:4
    x = dpp0_add<0x118, 0xF>(x);   // row_shr:8
    x = dpp0_add<0x142, 0xa>(x);   // row_bcast:15 -> rows 1,3
    x = dpp0_add<0x143, 0xc>(x);   // row_bcast:31 -> rows 2,3
    return x;
}

// ---- 64-sample window body for K2: branch-free, per-R constants folded ----
template<bool MASKED, int SP>
static __device__ __forceinline__ void k2_window(float fA, float fB, float fC,
                                                 float& s, int lo, int hi) {
    #pragma unroll
    for (int R = 0; R < 64; ++R) {
        float wy = (float)((R < 32) ? (2 * R + 65) : (2 * R - 63)) * 0.0078125f;
        float wx = 1.0f - wy;
        float h0 = (R < 32) ? fA : fB;
        float h1 = (R < 32) ? fB : fC;
        float fe;
        if (SP == 1 && R < 32)       fe = fB;
        else if (SP == 2 && R >= 32) fe = fB;
        else fe = __fadd_rn(__fmul_rn(h0, wx), __fmul_rn(h1, wy));
        float om = __fmul_rn(fe, omc_f());
        if (MASKED) om = (R >= lo && R < hi) ? om : 0.0f;   // fadd(s,+0)=s exact
        s = __fadd_rn(s, om);
    }
}

// K12 fat kernel. Blocks [0, 512): bit-exact f32 omega chunk scan. Blocks
// [512, 640): normalization.  DIAGNOSTIC: body repeated REP times (idempotent).
__global__ __launch_bounds__(64) void k12_scan_norm(const float* __restrict__ freqs,
                                                    const float* __restrict__ harms,
                                                    const float* __restrict__ amps,
                                                    float* __restrict__ ha,
                                                    float* __restrict__ substart,
                                                    float* __restrict__ tmod) {
    int blk = blockIdx.x;
    if (blk < K2BLOCKS) {
        int n = blk >> 5, c = blk & 31;
        int h = threadIdx.x;
        const float kf = (float)(h + 1);
        const int tbeg = c * CHUNK, tend = tbeg + CHUNK;
        #pragma unroll 1
        for (int rep = 0; rep < REP; ++rep) {
            const float* fr = freqs + n * NF;
            asm volatile("" : "+v"(fr));                    // force re-load per rep
            int t = tbeg & ~63;
            int q = t >> 6;
            float vA = fr[(q > 0) ? q - 1 : 0];
            float vB = fr[q];
            float vC = fr[(q + 1 < NF) ? q + 1 : NF - 1];
            float s = 0.0f;
            while (t < tend) {
                asm volatile("" : "+v"(vA), "+v"(vB), "+v"(vC), "+v"(s));  // opaque per window
                q = t >> 6;
                float vNext = fr[(q + 2 < NF) ? q + 2 : NF - 1];
                if (t >= tbeg)
                    substart[(((size_t)q) * NN + n) * NH + h] = s;  // exclusive prefix
                float fA = __fmul_rn(vA, kf), fB = __fmul_rn(vB, kf), fC = __fmul_rn(vC, kf);
                int lo = tbeg - t;
                int hi = tend - t;
                if (lo <= 0 && hi >= 64) {
                    if (q == 0)            k2_window<false, 1>(fA, fB, fC, s, 0, 64);
                    else if (q == NF - 1)  k2_window<false, 2>(fA, fB, fC, s, 0, 64);
                    else                   k2_window<false, 0>(fA, fB, fC, s, 0, 64);
                } else {
                    k2_window<true, 0>(fA, fB, fC, s, (lo > 0) ? lo : 0, (hi < 64) ? hi : 64);
                }
                vA = vB; vB = vC; vC = vNext;
                t += 64;
            }
            tmod[((size_t)c * NN + n) * NH + h] = fmodf(s, tpi_f());
        }
    } else {
        int blk2 = blk - K2BLOCKS;     // n * 8 + ftile
        int n = blk2 >> 3, ft = blk2 & 7;
        int lane = threadIdx.x;
        int f = (ft << 6) + lane;
        int fcl = (f < NF) ? f : NF - 1;
        __shared__ float sh[64][65];
        __shared__ float denl[64];
        #pragma unroll 1
        for (int rep = 0; rep < REP; ++rep) {
            const float* hb = harms + (size_t)n * NH * NF + fcl;
            asm volatile("" : "+v"(hb));
            float freq = freqs[n * NF + fcl];
            float den = 0.0f;
            #pragma unroll 8
            for (int h = 0; h < NH; ++h) {
                float hm = hb[(size_t)h * NF];
                hm = (__fmul_rn(freq, (float)(h + 1)) > 8000.0f) ? 0.0f : hm;
                sh[lane][h] = hm;
                den = __fadd_rn(den, hm);
            }
            denl[lane] = (den == 0.0f) ? 1e-7f : den;
            __syncthreads();
            int h = lane;
            #pragma unroll 8
            for (int ff = 0; ff < 64; ++ff) {
                int fo = (ft << 6) + ff;
                if (fo >= NF) break;
                float hm = sh[ff][h];
                float d  = denl[ff];
                float va = amps[n * NF + fo];
                ha[((size_t)fo * NN + n) * NH + h] = __fmul_rn(va, __fdiv_rn(hm, d));
            }
            __syncthreads();   // sh/denl rewritten next rep
        }
    }
}

// KS (transposed): lane = sample in window, wave = voice, loop over live harmonics.
// DIAGNOSTIC: body repeated REP times (idempotent).
__global__ __launch_bounds__(512) void ksyn(const float* __restrict__ freqs,
                                            const float* __restrict__ ha,
                                            const float* __restrict__ substart,
                                            const float* __restrict__ tmod,
                                            float* __restrict__ out) {
    int q = blockIdx.x % NWIN;
    int b = blockIdx.x / NWIN;
    int tid = threadIdx.x;
    int v = tid >> 6, l = tid & 63;
    int n = (b << 3) + v;

    __shared__ float4 pb[NVOICE][NH];      // {base0_rev, base1_rev, a0, a1} per (voice,h)
    __shared__ float vsum[NVOICE][WIN];    // per-voice audio

    int t0 = q << 6;
    int c0 = t0 / 1000;
    int tb = (c0 + 1) * 1000;
    int rb = (tb < t0 + WIN) ? (tb - t0) : 64;   // chunk-boundary lane (64 = none)
    int f1 = (q + 1 < NF) ? q + 1 : NF - 1;

    #pragma unroll 1
    for (int rep = 0; rep < REP; ++rep) {
        const float* tmb = tmod;
        const float* sbb = substart;
        const float* hab = ha;
        const float* frb = freqs;
        asm volatile("" : "+v"(tmb), "+v"(sbb), "+v"(hab), "+v"(frb));

        // ---- prologue, lane role = h ----
        {
            int h = l;
            const float* __restrict__ tm = tmb + (size_t)n * NH + h;   // [c][n][h]
            float cum = 0.0f;
            #pragma unroll
            for (int c = 0; c < NCHUNK - 1; ++c) {
                float tv = tm[(size_t)c * NN * NH];
                cum = __fadd_rn(cum, (c < c0) ? tv : 0.0f);  // +0 exact identity
            }
            float off0 = __fmul_rn(fmodf(cum, tpi_f()), inv2pi_f());
            float off1 = off0;
            if (rb < 64) {
                float cum2 = __fadd_rn(cum, tm[(size_t)c0 * NN * NH]);
                off1 = __fmul_rn(fmodf(cum2, tpi_f()), inv2pi_f());
            }
            float ss = sbb[((size_t)q * NN + n) * NH + h];
            float pr0 = __fmaf_rn(ss, inv2pi_f(), off0);
            float b0; asm("v_fract_f32 %0, %1" : "=v"(b0) : "v"(pr0));
            float a0 = hab[((size_t)q  * NN + n) * NH + h];
            float a1 = hab[((size_t)f1 * NN + n) * NH + h];
            pb[v][h] = make_float4(b0, off1, a0, a1);
        }

        // ---- window state, lane role = sample t = t0 + l ----
        const float* __restrict__ fr = frb + n * NF;
        float vAu = fr[(q > 0) ? q - 1 : 0];
        float vBu = fr[q];
        float vCu = fr[f1];
        asm volatile("" : "+v"(vAu), "+v"(vBu), "+v"(vCu));
        float wy = (float)((l < 32) ? (2 * l + 65) : (2 * l - 63)) * 0.0078125f;
        float wx = 1.0f - wy;
        bool mlo   = (l < 32);
        bool mEdge = (q == 0 && l < 32) || (q == NF - 1 && l >= 32);
        float wA = WT.wA[l], wB = WT.wB[l];

        float fb0 = mlo ? vAu : vBu;
        float fb1 = mlo ? vBu : vCu;
        float feB = __fadd_rn(__fmul_rn(fb0, wx), __fmul_rn(fb1, wy));
        feB = mEdge ? vBu : feB;
        float scanB = wave_incl_scan(feB);
        float bVal = __int_as_float(__builtin_amdgcn_readlane(__float_as_int(scanB),
                                                              (rb > 0) ? rb - 1 : 0));
        float sbAdj = scanB - ((l >= rb) ? bVal : 0.0f);

        float mnf = fminf(fminf(vAu, vBu), vCu);
        int hmax = min(64, (int)(__fdiv_rn(8000.5f, mnf)));
        hmax = __builtin_amdgcn_readfirstlane(hmax);

        float acc = 0.0f;
        float kf = 1.0f;
        #pragma unroll 4
        for (int hh = 0; hh < hmax; ++hh, kf += 1.0f) {
            float4 pbv = pb[v][hh];                          // uniform broadcast read
            float fA = __fmul_rn(vAu, kf), fB = __fmul_rn(vBu, kf), fC = __fmul_rn(vCu, kf);
            float h0 = mlo ? fA : fB;
            float h1 = mlo ? fB : fC;
            float fe = __fadd_rn(__fmul_rn(h0, wx), __fmul_rn(h1, wy));
            fe = mEdge ? fB : fe;                            // bit-exact freq env (for mask)
            float kor = __fmul_rn(kf, 6.25e-5f);             // (h+1)/16000 rev per unit
            float base = (l >= rb) ? pbv.y : pbv.x;
            float pr = __fmaf_rn(sbAdj, kor, base);
            float fr_, sv;
            asm("v_fract_f32 %0, %1" : "=v"(fr_) : "v"(pr));
            asm("v_sin_f32 %0, %1" : "=v"(sv) : "v"(fr_));   // sin(2pi*frac)
            float amp = __fadd_rn(__fmul_rn(pbv.w, wA), __fmul_rn(pbv.z, wB));
            amp = (fe > 8000.0f) ? 0.0f : amp;               // strict >, bit-exact fe
            acc = __fmaf_rn(sv, amp, acc);
        }
        vsum[v][l] = acc;
        __syncthreads();

        if (tid < WIN) {
            float s8 = 0.0f;
            #pragma unroll
            for (int vv = 0; vv < NVOICE; ++vv) s8 = __fadd_rn(s8, vsum[vv][tid]);
            out[(size_t)b * NT + t0 + tid] = __fmul_rn(0.02f, s8);
        }
        __syncthreads();   // vsum/pb rewritten next rep
    }
}

extern "C" void kernel_launch(void* const* d_in, const int* in_sizes, int n_in,
                              void* d_out, int out_size, void* d_ws, size_t ws_size,
                              hipStream_t stream) {
    (void)in_sizes; (void)n_in; (void)out_size; (void)ws_size;
    const float* freqs = (const float*)d_in[0];   // (2,8,500)
    const float* harms = (const float*)d_in[1];   // (2,8,64,500)
    const float* amps  = (const float*)d_in[2];   // (2,8,500)
    float* out = (float*)d_out;                   // (2,32000)

    // Workspace (floats): ha 512000 + substart 512000 + tmod 32768  (~4.2 MB)
    float* ws = (float*)d_ws;
    float* ha       = ws;                                    // [f][n][h]
    float* substart = ha + (size_t)NF * NN * NH;             // [window q][n][h]
    float* tmod     = substart + (size_t)NWIN * NN * NH;     // [c][n][h]

    hipLaunchKernelGGL(k12_scan_norm, dim3(K2BLOCKS + K1BLOCKS), dim3(64), 0, stream,
                       freqs, harms, amps, ha, substart, tmod);
    hipLaunchKernelGGL(ksyn, dim3(NB * NWIN), dim3(512), 0, stream,
                       freqs, ha, substart, tmod, out);
}

// Round 11
// 30.744 us; speedup vs baseline: 14.3994x; 14.3994x over previous
//
#include <hip/hip_runtime.h>
#include <math.h>

// Problem geometry (fixed by the reference)
#define NB 2
#define NVOICE 8
#define NN (NB * NVOICE)   // 16 series
#define NH 64              // harmonics
#define NF 500             // frames
#define NT 32000           // samples
#define NCHUNK 32          // angular_cumsum chunks of 1000
#define CHUNK 1000
#define NWIN 500           // one 64-sample window per synthesis block
#define WIN 64
#define K2BLOCKS (NN * NCHUNK)   // 512 chunk-scan blocks
#define K1BLOCKS (NN * 8)        // 128 normalization blocks

static __device__ __forceinline__ float tpi_f()    { return (float)(6.283185307179586); }
static __device__ __forceinline__ float omc_f()    { return (float)(6.283185307179586 / 16000.0); }
static __device__ __forceinline__ float inv2pi_f() { return (float)(1.0 / 6.283185307179586); }

// ---- compile-time Hann window table (f64 Taylor cos, rounded to f32) ----
constexpr double kPIO2 = 1.5707963267948966;
constexpr double d_cos_red(double r) {
    double r2 = r * r, term = 1.0, sum = 1.0;
    for (int k = 1; k <= 12; ++k) { term *= -r2 / (double)((2 * k - 1) * (2 * k)); sum += term; }
    return sum;
}
constexpr double d_sin_red(double r) {
    double r2 = r * r, term = r, sum = r;
    for (int k = 1; k <= 12; ++k) { term *= -r2 / (double)((2 * k) * (2 * k + 1)); sum += term; }
    return sum;
}
constexpr double d_cos(double x) {
    int k = 0; double r = x;
    while (r > kPIO2 * 0.5) { r -= kPIO2; ++k; }
    switch (k & 3) {
        case 0: return d_cos_red(r);
        case 1: return -d_sin_red(r);
        case 2: return -d_cos_red(r);
        default: return d_sin_red(r);
    }
}
struct WinT { float wA[64]; float wB[64]; };
constexpr WinT make_win() {
    WinT w{};
    for (int j = 0; j < 64; ++j) {
        float aA = (float)6.283185307179586 * (float)j * 0.0078125f;
        float aB = (float)6.283185307179586 * (float)(j + 64) * 0.0078125f;
        w.wA[j] = 0.5f - 0.5f * (float)d_cos((double)aA);   // win[r]    -> weights frame q+1
        w.wB[j] = 0.5f - 0.5f * (float)d_cos((double)aB);   // win[64+r] -> weights frame q
    }
    return w;
}
constexpr WinT WT = make_win();

// DPP helpers
template<int CTRL, int RMASK>
static __device__ __forceinline__ float dpp0_add(float x) {
    int y = __builtin_amdgcn_update_dpp(0, __float_as_int(x), CTRL, RMASK, 0xF, true);
    return x + __int_as_float(y);
}
// Inclusive 64-lane prefix sum (Hillis-Steele via DPP)
static __device__ __forceinline__ float wave_incl_scan(float x) {
    x = dpp0_add<0x111, 0xF>(x);   // row_shr:1
    x = dpp0_add<0x112, 0xF>(x);   // row_shr:2
    x = dpp0_add<0x114, 0xF>(x);   // row_shr:4
    x = dpp0_add<0x118, 0xF>(x);   // row_shr:8
    x = dpp0_add<0x142, 0xa>(x);   // row_bcast:15 -> rows 1,3
    x = dpp0_add<0x143, 0xc>(x);   // row_bcast:31 -> rows 2,3
    return x;
}

// ---- 64-sample window body for K2: branch-free, per-R constants folded ----
template<bool MASKED, int SP>
static __device__ __forceinline__ void k2_window(float fA, float fB, float fC,
                                                 float& s, int lo, int hi) {
    #pragma unroll
    for (int R = 0; R < 64; ++R) {
        float wy = (float)((R < 32) ? (2 * R + 65) : (2 * R - 63)) * 0.0078125f;
        float wx = 1.0f - wy;
        float h0 = (R < 32) ? fA : fB;
        float h1 = (R < 32) ? fB : fC;
        float fe;
        if (SP == 1 && R < 32)       fe = fB;
        else if (SP == 2 && R >= 32) fe = fB;
        else fe = __fadd_rn(__fmul_rn(h0, wx), __fmul_rn(h1, wy));
        float om = __fmul_rn(fe, omc_f());
        if (MASKED) om = (R >= lo && R < hi) ? om : 0.0f;   // fadd(s,+0)=s exact
        s = __fadd_rn(s, om);
    }
}

// K12 fat kernel. Blocks [0, 512): bit-exact f32 omega chunk scan (substart at
// every window start + chunk total mod 2pi). Blocks [512, 640): normalization.
__global__ __launch_bounds__(64) void k12_scan_norm(const float* __restrict__ freqs,
                                                    const float* __restrict__ harms,
                                                    const float* __restrict__ amps,
                                                    float* __restrict__ ha,
                                                    float* __restrict__ substart,
                                                    float* __restrict__ tmod) {
    int blk = blockIdx.x;
    if (blk < K2BLOCKS) {
        int n = blk >> 5, c = blk & 31;
        int h = threadIdx.x;
        const float kf = (float)(h + 1);
        const float* __restrict__ fr = freqs + n * NF;
        const int tbeg = c * CHUNK, tend = tbeg + CHUNK;
        int t = tbeg & ~63;
        int q = t >> 6;
        float vA = fr[(q > 0) ? q - 1 : 0];
        float vB = fr[q];
        float vC = fr[(q + 1 < NF) ? q + 1 : NF - 1];
        float s = 0.0f;
        while (t < tend) {
            q = t >> 6;
            float vNext = fr[(q + 2 < NF) ? q + 2 : NF - 1];
            if (t >= tbeg)
                substart[(((size_t)q) * NN + n) * NH + h] = s;  // exclusive prefix
            float fA = __fmul_rn(vA, kf), fB = __fmul_rn(vB, kf), fC = __fmul_rn(vC, kf);
            int lo = tbeg - t;
            int hi = tend - t;
            if (lo <= 0 && hi >= 64) {
                if (q == 0)            k2_window<false, 1>(fA, fB, fC, s, 0, 64);
                else if (q == NF - 1)  k2_window<false, 2>(fA, fB, fC, s, 0, 64);
                else                   k2_window<false, 0>(fA, fB, fC, s, 0, 64);
            } else {
                k2_window<true, 0>(fA, fB, fC, s, (lo > 0) ? lo : 0, (hi < 64) ? hi : 64);
            }
            vA = vB; vB = vC; vC = vNext;
            t += 64;
        }
        tmod[((size_t)c * NN + n) * NH + h] = fmodf(s, tpi_f());
    } else {
        int blk2 = blk - K2BLOCKS;     // n * 8 + ftile
        int n = blk2 >> 3, ft = blk2 & 7;
        int lane = threadIdx.x;
        int f = (ft << 6) + lane;
        int fcl = (f < NF) ? f : NF - 1;
        __shared__ float sh[64][65];
        __shared__ float denl[64];
        float freq = freqs[n * NF + fcl];
        float den = 0.0f;
        const float* __restrict__ hb = harms + (size_t)n * NH * NF + fcl;
        #pragma unroll 8
        for (int h = 0; h < NH; ++h) {
            float hm = hb[(size_t)h * NF];
            hm = (__fmul_rn(freq, (float)(h + 1)) > 8000.0f) ? 0.0f : hm;
            sh[lane][h] = hm;
            den = __fadd_rn(den, hm);
        }
        denl[lane] = (den == 0.0f) ? 1e-7f : den;
        __syncthreads();
        int h = lane;
        #pragma unroll 8
        for (int ff = 0; ff < 64; ++ff) {
            int fo = (ft << 6) + ff;
            if (fo >= NF) break;
            float hm = sh[ff][h];
            float d  = denl[ff];
            float va = amps[n * NF + fo];
            ha[((size_t)fo * NN + n) * NH + h] = __fmul_rn(va, __fdiv_rn(hm, d));
        }
    }
}

// ---- split harmonic loop: [0, hA) provably-unmasked (cheap), [hA, hmax) full ----
template<bool SPAN>
static __device__ __forceinline__ float harm_loop(int hA, int hmax, int rb, int l,
                                                  float sbAdj, float wx, float wy,
                                                  float vLo0, float vLo1,
                                                  float wA, float wB,
                                                  const float4* __restrict__ pbRow) {
    float acc = 0.0f;
    float kf = 1.0f;
    int hh = 0;
    #pragma unroll 4
    for (; hh < hA; ++hh, kf += 1.0f) {            // fe <= 8000 guaranteed: no mask
        float4 pbv = pbRow[hh];
        float base = SPAN ? ((l >= rb) ? pbv.y : pbv.x) : pbv.x;
        float kor = __fmul_rn(kf, 6.25e-5f);       // (h+1)/16000
        float pr = __fmaf_rn(sbAdj, kor, base);
        float fr_, sv;
        asm("v_fract_f32 %0, %1" : "=v"(fr_) : "v"(pr));
        asm("v_sin_f32 %0, %1" : "=v"(sv) : "v"(fr_));   // sin(2pi*frac)
        float amp = __fadd_rn(__fmul_rn(pbv.w, wA), __fmul_rn(pbv.z, wB));
        acc = __fmaf_rn(sv, amp, acc);
    }
    #pragma unroll 4
    for (; hh < hmax; ++hh, kf += 1.0f) {          // crossing band: bit-exact fe + mask
        float4 pbv = pbRow[hh];
        float h0 = __fmul_rn(vLo0, kf), h1 = __fmul_rn(vLo1, kf);
        float fe = __fadd_rn(__fmul_rn(h0, wx), __fmul_rn(h1, wy));
        float base = SPAN ? ((l >= rb) ? pbv.y : pbv.x) : pbv.x;
        float kor = __fmul_rn(kf, 6.25e-5f);
        float pr = __fmaf_rn(sbAdj, kor, base);
        float fr_, sv;
        asm("v_fract_f32 %0, %1" : "=v"(fr_) : "v"(pr));
        asm("v_sin_f32 %0, %1" : "=v"(sv) : "v"(fr_));
        float amp = __fadd_rn(__fmul_rn(pbv.w, wA), __fmul_rn(pbv.z, wB));
        amp = (fe > 8000.0f) ? 0.0f : amp;         // strict >, bit-exact fe
        acc = __fmaf_rn(sv, amp, acc);
    }
    return acc;
}

// KS (transposed): lane = sample in window, wave = voice, split harmonic loop.
__global__ __launch_bounds__(512) void ksyn(const float* __restrict__ freqs,
                                            const float* __restrict__ ha,
                                            const float* __restrict__ substart,
                                            const float* __restrict__ tmod,
                                            float* __restrict__ out) {
    int q = blockIdx.x % NWIN;
    int b = blockIdx.x / NWIN;
    int tid = threadIdx.x;
    int v = tid >> 6, l = tid & 63;
    int n = (b << 3) + v;

    __shared__ float4 pb[NVOICE][NH];      // {base0_rev, off1_rev, a0, a1} per (voice,h)
    __shared__ float vsum[NVOICE][WIN];    // per-voice audio

    int t0 = q << 6;
    int c0 = t0 / 1000;
    int tb = (c0 + 1) * 1000;
    int rb = (tb < t0 + WIN) ? (tb - t0) : 64;   // chunk-boundary lane (64 = none)
    int f1 = (q + 1 < NF) ? q + 1 : NF - 1;

    // ---- prologue, lane role = h ----
    {
        int h = l;
        const float* __restrict__ tm = tmod + (size_t)n * NH + h;   // [c][n][h]
        float cum = 0.0f;
        #pragma unroll
        for (int c = 0; c < NCHUNK - 1; ++c) {
            float tv = tm[(size_t)c * NN * NH];
            cum = __fadd_rn(cum, (c < c0) ? tv : 0.0f);  // +0 exact identity
        }
        // off in revolutions via fract (phase-tolerant replacement for fmodf)
        float cr0 = __fmul_rn(cum, inv2pi_f());
        float off0; asm("v_fract_f32 %0, %1" : "=v"(off0) : "v"(cr0));
        float off1 = off0;
        if (rb < 64) {
            float cum2 = __fadd_rn(cum, tm[(size_t)c0 * NN * NH]);
            float cr1 = __fmul_rn(cum2, inv2pi_f());
            asm("v_fract_f32 %0, %1" : "=v"(off1) : "v"(cr1));
        }
        float ss = substart[((size_t)q * NN + n) * NH + h];
        float pr0 = __fmaf_rn(ss, inv2pi_f(), off0);
        float b0; asm("v_fract_f32 %0, %1" : "=v"(b0) : "v"(pr0));
        float a0 = ha[((size_t)q  * NN + n) * NH + h];
        float a1 = ha[((size_t)f1 * NN + n) * NH + h];
        pb[v][h] = make_float4(b0, off1, a0, a1);
        // wave-private LDS row: no block barrier needed before own-row reads
    }

    // ---- window state, lane role = sample t = t0 + l ----
    const float* __restrict__ fr = freqs + n * NF;
    float vAu = fr[(q > 0) ? q - 1 : 0];     // lane-uniform
    float vBu = fr[q];
    float vCu = fr[f1];
    bool mlo   = (l < 32);
    bool mEdge = (q == 0 && mlo) || (q == NF - 1 && !mlo);
    float wy = (float)(mlo ? (2 * l + 65) : (2 * l - 63)) * 0.0078125f;
    float wx = 1.0f - wy;
    // Edge lanes: clamped lerp == fl(vB*k) exactly when (wx,wy)=(1,0), vLo0=vLo1=vB
    if (mEdge) { wx = 1.0f; wy = 0.0f; }
    float vLo0 = mEdge ? vBu : (mlo ? vAu : vBu);
    float vLo1 = mEdge ? vBu : (mlo ? vBu : vCu);
    float wA = WT.wA[l], wB = WT.wB[l];

    // base-freq envelope + one scan per window (phase factoring; tolerance-analyzed)
    float feB = __fadd_rn(__fmul_rn(vLo0, wx), __fmul_rn(vLo1, wy));
    float scanB = wave_incl_scan(feB);

    // live-harmonic bounds (conservative guards; exact mask still applied in band)
    float mxf = fmaxf(fmaxf(vAu, vBu), vCu);
    float mnf = fminf(fminf(vAu, vBu), vCu);
    int hmax = min(64, (int)(__fdiv_rn(8000.5f, mnf)));
    int hA   = min(hmax, (int)(__fdiv_rn(7999.96f, mxf)));
    hmax = __builtin_amdgcn_readfirstlane(hmax);
    hA   = __builtin_amdgcn_readfirstlane(hA);

    float acc;
    if (rb == 64) {
        acc = harm_loop<false>(hA, hmax, rb, l, scanB, wx, wy, vLo0, vLo1, wA, wB, pb[v]);
    } else {
        float bVal = __int_as_float(__builtin_amdgcn_readlane(__float_as_int(scanB), rb - 1));
        float sbAdj = scanB - ((l >= rb) ? bVal : 0.0f);
        acc = harm_loop<true>(hA, hmax, rb, l, sbAdj, wx, wy, vLo0, vLo1, wA, wB, pb[v]);
    }
    vsum[v][l] = acc;
    __syncthreads();

    if (tid < WIN) {
        float s8 = 0.0f;
        #pragma unroll
        for (int vv = 0; vv < NVOICE; ++vv) s8 = __fadd_rn(s8, vsum[vv][tid]);
        out[(size_t)b * NT + t0 + tid] = __fmul_rn(0.02f, s8);
    }
}

extern "C" void kernel_launch(void* const* d_in, const int* in_sizes, int n_in,
                              void* d_out, int out_size, void* d_ws, size_t ws_size,
                              hipStream_t stream) {
    (void)in_sizes; (void)n_in; (void)out_size; (void)ws_size;
    const float* freqs = (const float*)d_in[0];   // (2,8,500)
    const float* harms = (const float*)d_in[1];   // (2,8,64,500)
    const float* amps  = (const float*)d_in[2];   // (2,8,500)
    float* out = (float*)d_out;                   // (2,32000)

    // Workspace (floats): ha 512000 + substart 512000 + tmod 32768  (~4.2 MB)
    float* ws = (float*)d_ws;
    float* ha       = ws;                                    // [f][n][h]
    float* substart = ha + (size_t)NF * NN * NH;             // [window q][n][h]
    float* tmod     = substart + (size_t)NWIN * NN * NH;     // [c][n][h]

    hipLaunchKernelGGL(k12_scan_norm, dim3(K2BLOCKS + K1BLOCKS), dim3(64), 0, stream,
                       freqs, harms, amps, ha, substart, tmod);
    hipLaunchKernelGGL(ksyn, dim3(NB * NWIN), dim3(512), 0, stream,
                       freqs, ha, substart, tmod, out);
}

// Round 12
// 18.442 us; speedup vs baseline: 24.0040x; 1.6670x over previous
//
#include <hip/hip_runtime.h>
#include <math.h>

// Problem geometry (fixed by the reference)
#define NB 2
#define NVOICE 8
#define NN (NB * NVOICE)   // 16 series
#define NH 64              // harmonics
#define NF 500             // frames
#define NT 32000           // samples
#define NWIN 500           // one 64-sample window per block
#define WIN 64

static __device__ __forceinline__ float inv2pi_f() { return (float)(1.0 / 6.283185307179586); }

// ---- compile-time Hann window table (f64 Taylor cos, rounded to f32) ----
constexpr double kPIO2 = 1.5707963267948966;
constexpr double d_cos_red(double r) {
    double r2 = r * r, term = 1.0, sum = 1.0;
    for (int k = 1; k <= 12; ++k) { term *= -r2 / (double)((2 * k - 1) * (2 * k)); sum += term; }
    return sum;
}
constexpr double d_sin_red(double r) {
    double r2 = r * r, term = r, sum = r;
    for (int k = 1; k <= 12; ++k) { term *= -r2 / (double)((2 * k) * (2 * k + 1)); sum += term; }
    return sum;
}
constexpr double d_cos(double x) {
    int k = 0; double r = x;
    while (r > kPIO2 * 0.5) { r -= kPIO2; ++k; }
    switch (k & 3) {
        case 0: return d_cos_red(r);
        case 1: return -d_sin_red(r);
        case 2: return -d_cos_red(r);
        default: return d_sin_red(r);
    }
}
struct WinT { float wA[64]; float wB[64]; };
constexpr WinT make_win() {
    WinT w{};
    for (int j = 0; j < 64; ++j) {
        float aA = (float)6.283185307179586 * (float)j * 0.0078125f;
        float aB = (float)6.283185307179586 * (float)(j + 64) * 0.0078125f;
        w.wA[j] = 0.5f - 0.5f * (float)d_cos((double)aA);   // win[r]    -> weights frame q+1
        w.wB[j] = 0.5f - 0.5f * (float)d_cos((double)aB);   // win[64+r] -> weights frame q
    }
    return w;
}
constexpr WinT WT = make_win();

// DPP helpers
template<int CTRL, int RMASK>
static __device__ __forceinline__ float dpp0_add(float x) {
    int y = __builtin_amdgcn_update_dpp(0, __float_as_int(x), CTRL, RMASK, 0xF, true);
    return x + __int_as_float(y);
}
// Inclusive 64-lane prefix sum (Hillis-Steele via DPP)
static __device__ __forceinline__ float wave_incl_scan(float x) {
    x = dpp0_add<0x111, 0xF>(x);   // row_shr:1
    x = dpp0_add<0x112, 0xF>(x);   // row_shr:2
    x = dpp0_add<0x114, 0xF>(x);   // row_shr:4
    x = dpp0_add<0x118, 0xF>(x);   // row_shr:8
    x = dpp0_add<0x142, 0xa>(x);   // row_bcast:15 -> rows 1,3
    x = dpp0_add<0x143, 0xc>(x);   // row_bcast:31 -> rows 2,3
    return x;
}
// Full 64-lane sum broadcast to all lanes (prologue only)
static __device__ __forceinline__ float wave_sum_all_f(float x) {
    #pragma unroll
    for (int m = 1; m < 64; m <<= 1) x += __shfl_xor(x, m, 64);
    return x;
}
static __device__ __forceinline__ double wave_sum_all_d(double x) {
    #pragma unroll
    for (int m = 1; m < 64; m <<= 1) x += __shfl_xor(x, m, 64);
    return x;
}

// Single fused kernel: block = (b, window q); 512 thr = 8 voices x 64 lanes.
// Phase via exact f64 closed form: D(64q) = 64*Sum_{j<q} fr[j] + 8*(fr[q]-fr[q-1]).
__global__ __launch_bounds__(512) void ksyn_all(const float* __restrict__ freqs,
                                                const float* __restrict__ harms,
                                                const float* __restrict__ amps,
                                                float* __restrict__ out) {
    int q = blockIdx.x % NWIN;
    int b = blockIdx.x / NWIN;
    int tid = threadIdx.x;
    int v = tid >> 6, l = tid & 63;
    int n = (b << 3) + v;

    __shared__ float4 pb[NVOICE][NH];      // {base_rev, a1, a0, pad} per (voice,h)
    __shared__ float vsum[NVOICE][WIN];    // per-voice audio

    int f1 = (q + 1 < NF) ? q + 1 : NF - 1;
    const float* __restrict__ fr = freqs + n * NF;

    // ---- prologue, lane role = h ----
    {
        int h = l;
        float kf = (float)(h + 1);
        // f64 frame prefix: lanes batch-load fr[j] (coalesced), masked j < q
        double accd = 0.0;
        for (int j0 = 0; j0 < q; j0 += 64) {
            int j = j0 + l;
            float fv = (j < q) ? fr[j] : 0.0f;
            accd += (double)fv;
        }
        double S = wave_sum_all_d(accd);
        double D = 64.0 * S;
        if (q > 0) D += 8.0 * ((double)fr[q] - (double)fr[q - 1]);
        double rk = (double)(h + 1) * (D * (1.0 / 16000.0));  // revolutions at window start
        rk -= floor(rk);
        float base = (float)rk;
        // normalization for frames q, f1 (bit-exact mask, butterfly denom)
        const float* __restrict__ hb = harms + ((size_t)n * NH + h) * NF;
        float fq0 = fr[q], fq1 = fr[f1];
        float hm0 = hb[q], hm1 = hb[f1];
        hm0 = (__fmul_rn(fq0, kf) > 8000.0f) ? 0.0f : hm0;
        hm1 = (__fmul_rn(fq1, kf) > 8000.0f) ? 0.0f : hm1;
        float d0 = wave_sum_all_f(hm0), d1 = wave_sum_all_f(hm1);
        d0 = (d0 == 0.0f) ? 1e-7f : d0;
        d1 = (d1 == 0.0f) ? 1e-7f : d1;
        float va0 = amps[n * NF + q], va1 = amps[n * NF + f1];
        float a0 = __fmul_rn(va0, __fdiv_rn(hm0, d0));
        float a1 = __fmul_rn(va1, __fdiv_rn(hm1, d1));
        pb[v][h] = make_float4(base, a1, a0, 0.0f);
        // wave-private LDS row; DS ops in-order per wave -> no block barrier needed
    }

    // ---- main, lane role = sample t = 64q + l ----
    float vAu = fr[(q > 0) ? q - 1 : 0];     // lane-uniform
    float vBu = fr[q];
    float vCu = fr[f1];
    bool mlo   = (l < 32);
    bool mEdge = (q == 0 && mlo) || (q == NF - 1 && !mlo);
    float wy = (float)(mlo ? (2 * l + 65) : (2 * l - 63)) * 0.0078125f;
    float wx = 1.0f - wy;
    if (mEdge) { wx = 1.0f; wy = 0.0f; }     // clamped lerp == fl(vB*k) exactly
    float vLo0 = mEdge ? vBu : (mlo ? vAu : vBu);
    float vLo1 = mEdge ? vBu : (mlo ? vBu : vCu);
    float wA = WT.wA[l], wB = WT.wB[l];

    // in-window base-envelope inclusive scan (phase-tolerant), pre-scaled to rev/k
    float feB = __fadd_rn(__fmul_rn(vLo0, wx), __fmul_rn(vLo1, wy));
    float scanB = wave_incl_scan(feB);
    float scanC = __fmul_rn(scanB, 6.25e-5f);   // = scan/16000: revolutions per unit k

    // live-harmonic bounds (conservative guards; exact mask still applied in band)
    float mxf = fmaxf(fmaxf(vAu, vBu), vCu);
    float mnf = fminf(fminf(vAu, vBu), vCu);
    int hmax = min(64, (int)(__fdiv_rn(8000.5f, mnf)));
    int hA   = min(hmax, (int)(__fdiv_rn(7999.96f, mxf)));
    hmax = __builtin_amdgcn_readfirstlane(hmax);
    hA   = __builtin_amdgcn_readfirstlane(hA);

    const float4* __restrict__ pbRow = pb[v];
    float accA = 0.0f, accB = 0.0f;          // audio = wA*accA + wB*accB (factored amp)
    float kf = 1.0f;
    int hh = 0;
    #pragma unroll 4
    for (; hh < hA; ++hh, kf += 1.0f) {      // fe <= 8000 guaranteed: no mask
        float4 pbv = pbRow[hh];
        float pr = __fmaf_rn(scanC, kf, pbv.x);
        float fr_, sv;
        asm("v_fract_f32 %0, %1" : "=v"(fr_) : "v"(pr));
        asm("v_sin_f32 %0, %1" : "=v"(sv) : "v"(fr_));   // sin(2pi*frac)
        accA = __fmaf_rn(sv, pbv.y, accA);
        accB = __fmaf_rn(sv, pbv.z, accB);
    }
    #pragma unroll 4
    for (; hh < hmax; ++hh, kf += 1.0f) {    // crossing band: bit-exact fe + mask
        float4 pbv = pbRow[hh];
        float h0 = __fmul_rn(vLo0, kf), h1 = __fmul_rn(vLo1, kf);
        float fe = __fadd_rn(__fmul_rn(h0, wx), __fmul_rn(h1, wy));
        float pr = __fmaf_rn(scanC, kf, pbv.x);
        float fr_, sv;
        asm("v_fract_f32 %0, %1" : "=v"(fr_) : "v"(pr));
        asm("v_sin_f32 %0, %1" : "=v"(sv) : "v"(fr_));
        sv = (fe > 8000.0f) ? 0.0f : sv;     // strict >, bit-exact fe
        accA = __fmaf_rn(sv, pbv.y, accA);
        accB = __fmaf_rn(sv, pbv.z, accB);
    }
    vsum[v][l] = __fadd_rn(__fmul_rn(accA, wA), __fmul_rn(accB, wB));
    __syncthreads();

    if (tid < WIN) {
        float s8 = 0.0f;
        #pragma unroll
        for (int vv = 0; vv < NVOICE; ++vv) s8 = __fadd_rn(s8, vsum[vv][tid]);
        out[(size_t)b * NT + (q << 6) + tid] = __fmul_rn(0.02f, s8);
    }
}

extern "C" void kernel_launch(void* const* d_in, const int* in_sizes, int n_in,
                              void* d_out, int out_size, void* d_ws, size_t ws_size,
                              hipStream_t stream) {
    (void)in_sizes; (void)n_in; (void)out_size; (void)d_ws; (void)ws_size;
    const float* freqs = (const float*)d_in[0];   // (2,8,500)
    const float* harms = (const float*)d_in[1];   // (2,8,64,500)
    const float* amps  = (const float*)d_in[2];   // (2,8,500)
    float* out = (float*)d_out;                   // (2,32000)

    hipLaunchKernelGGL(ksyn_all, dim3(NB * NWIN), dim3(512), 0, stream,
                       freqs, harms, amps, out);
}